// Round 7
// baseline (1007.438 us; speedup 1.0000x reference)
//
#include <hip/hip_runtime.h>
#include <stdint.h>
#include <float.h>

// x[4096,256] f32, keys[65536,256] f32, values[65536,10] f32, k=8 (hardcoded).
#define B_ROWS 4096
#define N_KEYS 65536
#define DDIM 256
#define NCH 10

#define NSPLIT 32
#define SPLIT_KEYS (N_KEYS / NSPLIT)       // 2048
#define ROWS_PER_BLK 256
#define CHUNK_KEYS 64
#define NCHUNK (SPLIT_KEYS / CHUNK_KEYS)   // 32

typedef float f32x4 __attribute__((ext_vector_type(4)));
typedef short bf16x8 __attribute__((ext_vector_type(8)));

static __device__ __forceinline__ unsigned short f2bf(float f) {
  unsigned u = __float_as_uint(f);
  return (unsigned short)((u + 0x7FFFu + ((u >> 16) & 1u)) >> 16);
}
static __device__ __forceinline__ unsigned ford(float f) {
  unsigned u = __float_as_uint(f);
  return u ^ ((unsigned)((int)u >> 31) | 0x80000000u);
}
static __device__ __forceinline__ unsigned long long shfl_xor_u64(unsigned long long v, int m) {
  unsigned lo = __shfl_xor((unsigned)v, m, 64);
  unsigned hi = __shfl_xor((unsigned)(v >> 32), m, 64);
  return ((unsigned long long)hi << 32) | lo;
}
static __device__ __forceinline__ double shfl_xor_f64(double v, int m) {
  return __longlong_as_double((long long)shfl_xor_u64((unsigned long long)__double_as_longlong(v), m));
}
static __device__ __forceinline__ void gl_lds16(const void* g, void* l) {
  __builtin_amdgcn_global_load_lds(
      (const __attribute__((address_space(1))) unsigned int*)g,
      (__attribute__((address_space(3))) unsigned int*)l, 16, 0, 0);
}

// ---------------------------------------------------------------------------
// transpose_keys: bf16-convert + transpose + fused ksq. Output: per 64-key
// record [doct 0..31][key 0..63][16B] (32KB) so knn_main staging is a LINEAR
// copy and A-frag ds_read_b128s are 256B-contiguous per 16-lane phase.
// ---------------------------------------------------------------------------
__global__ __launch_bounds__(256) void transpose_keys(const float* __restrict__ keys,
                                                      unsigned char* __restrict__ kbf,
                                                      float* __restrict__ ksq) {
  __shared__ __align__(16) unsigned char T[128 * 512];
  const int t = threadIdx.x;
  const int lane = t & 63;
  const float4* src = (const float4*)(keys + (size_t)blockIdx.x * 128 * DDIM);
#pragma unroll
  for (int j = 0; j < 32; ++j) {
    int g = j * 256 + t;
    float4 v = src[g];
    int key = g >> 6;
    int u = lane >> 1, sub = lane & 1;
    unsigned lo = ((unsigned)f2bf(v.y) << 16) | f2bf(v.x);
    unsigned hi2 = ((unsigned)f2bf(v.w) << 16) | f2bf(v.z);
    unsigned long long p = ((unsigned long long)hi2 << 32) | lo;
    *(unsigned long long*)&T[key * 512 + ((u ^ (key & 7)) << 4) + (sub << 3)] = p;
    float ss = v.x * v.x + v.y * v.y + v.z * v.z + v.w * v.w;
#pragma unroll
    for (int off = 32; off; off >>= 1) ss += __shfl_xor(ss, off, 64);
    if (lane == 0) ksq[blockIdx.x * 128 + key] = ss;
  }
  __syncthreads();
  uint4* dst = (uint4*)(kbf + (size_t)blockIdx.x * 65536);
#pragma unroll
  for (int j = 0; j < 16; ++j) {
    int ou = j * 256 + t;
    int c64 = ou >> 11, rem = ou & 2047;
    int koct = rem >> 6, key64 = rem & 63;
    int keyl = c64 * 64 + key64;
    dst[ou] = *(const uint4*)&T[keyl * 512 + ((koct ^ (keyl & 7)) << 4)];
  }
}

// ---------------------------------------------------------------------------
// knn_main: 512 thr = 8 waves = 2 key-groups (kg, 32 keys) x 4 row-quads
// (rq, 64 rows = 4 register row-sets of 16). Block: 256 rows x one split
// (2048 keys) in 32 chunks of 64 keys. Grid 512 = 2 blocks/CU (16 waves/CU,
// 4/SIMD): two independent barrier domains per SIMD hide each other's
// waitcnt/barrier slack (r5-vs-r6 A/B isolated occupancy as the lever).
// feed-4: each A-frag ds_read_b128 feeds 4 MFMAs. Counted-vmcnt double
// buffer: vmcnt(6) at tile entry, lgkmcnt(0) at exit; never drains.
// Selection: tau filter + append (8 streams/row = hi x kg; tau_row = max of
// the 8 stream minima >= row's true 8th-best; overflow -> exact rescan in
// refine, so correctness is unconditional).
// ---------------------------------------------------------------------------
__global__ __launch_bounds__(512, 4) void knn_main(
    const float* __restrict__ x,
    const unsigned char* __restrict__ kbf,
    const float* __restrict__ ksqg,
    unsigned int* __restrict__ pools,
    unsigned int* __restrict__ counts,
    int CAP) {
  __shared__ __align__(16) unsigned char tiles[2][32768]; // 64KB double buffer
  __shared__ float tauh[2][256];                          // [kg][row]
  __shared__ unsigned int rowcnt[256];

  const int t = threadIdx.x;
  const int lane = t & 63;
  const int wv = t >> 6;       // 0..7
  const int kg = wv & 1;       // key group (32 keys)
  const int rq = wv >> 1;      // row quarter (64 rows)
  const int lo4 = lane & 15;
  const int hi = lane >> 4;

  const int split = blockIdx.x & (NSPLIT - 1);
  const int rb = (blockIdx.x >> 5) * ROWS_PER_BLK;
  const int sb = split * SPLIT_KEYS;

  // ---- x fragments: 4 row-sets of 16 rows, resident all kernel (128 VGPR)
  bf16x8 xb[4][8];
#pragma unroll
  for (int st = 0; st < 4; ++st) {
    const float* xr = x + (size_t)(rb + rq * 64 + st * 16 + lo4) * DDIM;
#pragma unroll
    for (int s = 0; s < 8; ++s) {
      const float* p = xr + s * 32 + hi * 8;
      float4 a = *(const float4*)p, b = *(const float4*)(p + 4);
      union { unsigned short us[8]; bf16x8 v; } u;
      u.us[0]=f2bf(a.x); u.us[1]=f2bf(a.y); u.us[2]=f2bf(a.z); u.us[3]=f2bf(a.w);
      u.us[4]=f2bf(b.x); u.us[5]=f2bf(b.y); u.us[6]=f2bf(b.z); u.us[7]=f2bf(b.w);
      xb[st][s] = u.v;
    }
  }

  if (t < 256) rowcnt[t] = 0;

  const unsigned char* srcbase = kbf + ((size_t)(split * NCHUNK) << 15);

  auto STAGE = [&](int c, int buf) { // linear 32KB, 4 x 16B per thread
    const unsigned char* src = srcbase + ((size_t)c << 15);
    unsigned char* wb = (unsigned char*)tiles[buf] + ((wv * 64) << 4);
#pragma unroll
    for (int i = 0; i < 4; ++i)
      gl_lds16(src + (((i * 512) + t) << 4), wb + ((i * 512) << 4));
  };

  const int kqoff = kg * 32 + hi * 4;
  float4 kqc0 = *(const float4*)(ksqg + sb + kqoff);
  float4 kqc1 = *(const float4*)(ksqg + sb + kqoff + 16);

  float smin[4] = {FLT_MAX, FLT_MAX, FLT_MAX, FLT_MAX};
  f32x4 acc[4][2];

  auto COMPUTE = [&](int c) {
    const unsigned char* tile = tiles[c & 1];
#pragma unroll
    for (int st = 0; st < 4; ++st) { acc[st][0] = 0.0f; acc[st][1] = 0.0f; }
#pragma unroll
    for (int s = 0; s < 8; ++s) {
      const unsigned char* rp = tile + (s * 4 + hi) * 1024 + (kg * 32 + lo4) * 16;
      bf16x8 af0 = *(const bf16x8*)rp;
      bf16x8 af1 = *(const bf16x8*)(rp + 256);
#pragma unroll
      for (int st = 0; st < 4; ++st) {
        acc[st][0] = __builtin_amdgcn_mfma_f32_16x16x32_bf16(af0, xb[st][s], acc[st][0], 0, 0, 0);
        acc[st][1] = __builtin_amdgcn_mfma_f32_16x16x32_bf16(af1, xb[st][s], acc[st][1], 0, 0, 0);
      }
    }
  };

  auto SELECT = [&](int c, const float* trd) { // scores + smin + gated append
    const int kbase = c * CHUNK_KEYS + kg * 32;
#pragma unroll
    for (int st = 0; st < 4; ++st) {
      float sc[8];
#pragma unroll
      for (int i = 0; i < 4; ++i) {
        sc[i]     = fmaf(-2.0f, acc[st][0][i], ((const float*)&kqc0)[i]);
        sc[4 + i] = fmaf(-2.0f, acc[st][1][i], ((const float*)&kqc1)[i]);
      }
      float m = sc[0];
#pragma unroll
      for (int e = 1; e < 8; ++e) m = fminf(m, sc[e]);
      smin[st] = fminf(smin[st], m);
      if (m <= trd[st]) { // rare
        const int lrow = rq * 64 + st * 16 + lo4;
        const size_t pb = ((size_t)(rb + lrow) * NSPLIT + split) * (size_t)CAP;
#pragma unroll
        for (int e = 0; e < 8; ++e) {
          if (sc[e] <= trd[st]) {
            unsigned slot = atomicAdd(&rowcnt[lrow], 1u);
            if ((int)slot < CAP)
              pools[pb + slot] = (ford(sc[e]) & 0xFFFFF800u)
                               | (unsigned)(kbase + (e >> 2) * 16 + hi * 4 + (e & 3));
          }
        }
      }
    }
  };

  auto PUBLISH = [&]() {
#pragma unroll
    for (int st = 0; st < 4; ++st) {
      float v = smin[st];
      v = fmaxf(v, __shfl_xor(v, 16, 64));
      v = fmaxf(v, __shfl_xor(v, 32, 64)); // max over the 4 hi-stream minima
      if (hi == 0) tauh[kg][rq * 64 + st * 16 + lo4] = v;
    }
  };

  // ---- prologue + peeled chunk 0 (no appends before tau exists)
  STAGE(0, 0);
  __syncthreads();

  STAGE(1, 1);
  float4 kqn0 = *(const float4*)(ksqg + sb + 64 + kqoff);
  float4 kqn1 = *(const float4*)(ksqg + sb + 64 + kqoff + 16);
  COMPUTE(0);
  {
    float tneg[4] = {-FLT_MAX, -FLT_MAX, -FLT_MAX, -FLT_MAX};
    SELECT(0, tneg); // smin only, gate never fires
  }
  PUBLISH();
  __syncthreads(); // tau visible (also drains stage(1) — prologue only)
  {
    float trd[4];
#pragma unroll
    for (int st = 0; st < 4; ++st) {
      int lr = rq * 64 + st * 16 + lo4;
      trd[st] = fmaxf(tauh[0][lr], tauh[1][lr]);
    }
    SELECT(0, trd); // append chunk 0 with fresh tau
  }
  kqc0 = kqn0; kqc1 = kqn1;

#pragma unroll 1
  for (int c = 1; c < NCHUNK; ++c) {
    const int cn = (c + 1 < NCHUNK) ? c + 1 : c; // uniform tail (re-stage ok)
    STAGE(cn, (c + 1) & 1);
    float4 kn0 = *(const float4*)(ksqg + sb + cn * 64 + kqoff);
    float4 kn1 = *(const float4*)(ksqg + sb + cn * 64 + kqoff + 16);
    float trd[4];
#pragma unroll
    for (int st = 0; st < 4; ++st) {
      int lr = rq * 64 + st * 16 + lo4;
      trd[st] = fmaxf(tauh[0][lr], tauh[1][lr]); // lagged tau: valid bound
    }
    asm volatile("s_waitcnt vmcnt(6)" ::: "memory"); // chunk c landed; c+1 in flight
    __builtin_amdgcn_s_barrier();
    __builtin_amdgcn_sched_barrier(0);
    COMPUTE(c);
    SELECT(c, trd);
    PUBLISH();
    kqc0 = kn0; kqc1 = kn1;
    asm volatile("s_waitcnt lgkmcnt(0)" ::: "memory"); // tile reads + tau writes done
    __builtin_amdgcn_s_barrier();
  }

  __syncthreads();
  if (t < 256) counts[(size_t)(rb + t) * NSPLIT + split] = rowcnt[t];
}

// ---------------------------------------------------------------------------
// knn_refine: per row (1 wave): scan the row's 32 pools (or exact-rescan any
// overflowed split) into per-lane top-8, tournament top-24 by quantized
// score, fp64-exact recompute, true top-8 (idx tiebreak), average values.
// ---------------------------------------------------------------------------
__global__ __launch_bounds__(64) void knn_refine(
    const float* __restrict__ x,
    const float* __restrict__ keys,
    const float* __restrict__ ksq,
    const float* __restrict__ values,
    const unsigned int* __restrict__ pools,
    const unsigned int* __restrict__ counts,
    int CAP,
    float* __restrict__ out) {
  __shared__ float4 xl[64];
  const int row = blockIdx.x;
  const int lane = threadIdx.x;

  xl[lane] = ((const float4*)(x + (size_t)row * DDIM))[lane];
  __syncthreads();

  unsigned long long h[8];
#pragma unroll
  for (int i = 0; i < 8; ++i) h[i] = ~0ULL;

  auto insert = [&](unsigned long long v) {
    if (v < h[7]) {
#pragma unroll
      for (int j = 7; j >= 1; --j) {
        unsigned long long a = h[j - 1];
        unsigned long long mx = a > v ? a : v;
        h[j] = (v < h[j]) ? mx : h[j];
      }
      h[0] = h[0] < v ? h[0] : v;
    }
  };

  for (int s = 0; s < NSPLIT; ++s) {
    unsigned cnt = counts[(size_t)row * NSPLIT + s];
    if ((int)cnt <= CAP) {
      const unsigned int* pp = pools + ((size_t)row * NSPLIT + s) * (size_t)CAP;
      for (int i = lane; i < (int)cnt; i += 64) {
        unsigned p = pp[i];
        unsigned long long v = ((unsigned long long)p << 16)
                             | (unsigned)(s * SPLIT_KEYS + (p & 0x7FFu));
        insert(v);
      }
    } else {
      // overflow fallback: exact fp32 rescan of this split
      for (int kk = lane; kk < SPLIT_KEYS; kk += 64) {
        int gk = s * SPLIT_KEYS + kk;
        const float4* kr = (const float4*)(keys + (size_t)gk * DDIM);
        float acc = 0.f;
#pragma unroll 8
        for (int d = 0; d < 64; ++d) {
          float4 kv = kr[d], xv = xl[d];
          acc = fmaf(kv.x, xv.x, acc); acc = fmaf(kv.y, xv.y, acc);
          acc = fmaf(kv.z, xv.z, acc); acc = fmaf(kv.w, xv.w, acc);
        }
        float sc = fmaf(-2.0f, acc, ksq[gk]);
        unsigned p = (ford(sc) & 0xFFFFF800u) | (unsigned)kk;
        insert(((unsigned long long)p << 16) | (unsigned)gk);
      }
    }
  }

  // ---- tournament: top-24 by quantized score (u64 unique: gk in low bits)
  int myidx = 0;
#pragma unroll 1
  for (int r = 0; r < 24; ++r) {
    unsigned long long m = h[0];
#pragma unroll
    for (int off = 32; off; off >>= 1) {
      unsigned long long o = shfl_xor_u64(m, off);
      m = o < m ? o : m;
    }
    if (lane == r) myidx = (int)(m & 0xFFFFu);
    if (h[0] == m) {
#pragma unroll
      for (int i = 0; i < 7; ++i) h[i] = h[i + 1];
      h[7] = ~0ULL;
    }
  }

  // ---- exact fp64 distance for my candidate
  double dv = 1e300;
  if (lane < 24) {
    const float4* kr = (const float4*)(keys + (size_t)myidx * DDIM);
    double s = 0.0;
#pragma unroll 8
    for (int d = 0; d < 64; ++d) {
      float4 kv = kr[d], xv = xl[d];
      double d0 = (double)xv.x - (double)kv.x;
      double d1 = (double)xv.y - (double)kv.y;
      double d2 = (double)xv.z - (double)kv.z;
      double d3 = (double)xv.w - (double)kv.w;
      s += d0 * d0 + d1 * d1 + d2 * d2 + d3 * d3;
    }
    dv = s;
  }

  int di = myidx;
  int chosen[8];
#pragma unroll
  for (int r = 0; r < 8; ++r) {
    double m = dv; int mi = di;
#pragma unroll
    for (int off = 32; off; off >>= 1) {
      double om = shfl_xor_f64(m, off);
      int omi = __shfl_xor(mi, off, 64);
      if (om < m || (om == m && omi < mi)) { m = om; mi = omi; }
    }
    chosen[r] = mi;
    if (di == mi && dv < 1e300) dv = 1e300;
  }

  if (lane < NCH) {
    double a = 0.0;
#pragma unroll
    for (int r = 0; r < 8; ++r) a += (double)values[(size_t)chosen[r] * NCH + lane];
    out[row * NCH + lane] = (float)(a * 0.125);
  }
}

// ---------------------------------------------------------------------------
extern "C" void kernel_launch(void* const* d_in, const int* in_sizes, int n_in,
                              void* d_out, int out_size, void* d_ws, size_t ws_size,
                              hipStream_t stream) {
  (void)in_sizes; (void)n_in; (void)out_size;
  const float* x      = (const float*)d_in[0];
  const float* keys   = (const float*)d_in[1];
  const float* values = (const float*)d_in[2];
  float* out = (float*)d_out;

  char* ws = (char*)d_ws;
  unsigned char* kbf = (unsigned char*)ws;                     // 32 MB transposed bf16 keys
  float* ksq   = (float*)(ws + 33554432);                      // 256 KB
  unsigned int* counts = (unsigned int*)(ws + 33554432 + 262144); // 512 KB (4096*32*4)
  unsigned int* pools  = (unsigned int*)(ws + 33554432 + 262144 + 524288);

  size_t base = 33554432 + 262144 + 524288;
  size_t cap = (ws_size > base) ? (ws_size - base) / ((size_t)B_ROWS * NSPLIT * 4) : 32;
  if (cap < 32) cap = 32;
  if (cap > 512) cap = 512;
  int CAP = (int)cap;

  transpose_keys<<<N_KEYS / 128, 256, 0, stream>>>(keys, kbf, ksq);
  knn_main<<<(B_ROWS / ROWS_PER_BLK) * NSPLIT, 512, 0, stream>>>(
      x, kbf, ksq, pools, counts, CAP);
  knn_refine<<<B_ROWS, 64, 0, stream>>>(x, keys, ksq, values, pools, counts, CAP, out);
}

// Round 8
// 919.088 us; speedup vs baseline: 1.0961x; 1.0961x over previous
//
#include <hip/hip_runtime.h>
#include <stdint.h>
#include <float.h>

// x[4096,256] f32, keys[65536,256] f32, values[65536,10] f32, k=8 (hardcoded).
#define B_ROWS 4096
#define N_KEYS 65536
#define DDIM 256
#define NCH 10

#define NSPLIT 32
#define SPLIT_KEYS (N_KEYS / NSPLIT)   // 2048
#define NSTEP (SPLIT_KEYS / 16)        // 128 16-key steps

typedef float f32x4 __attribute__((ext_vector_type(4)));
typedef short bf16x8 __attribute__((ext_vector_type(8)));

static __device__ __forceinline__ unsigned short f2bf(float f) {
  unsigned u = __float_as_uint(f);
  return (unsigned short)((u + 0x7FFFu + ((u >> 16) & 1u)) >> 16);
}
static __device__ __forceinline__ unsigned ford(float f) {
  unsigned u = __float_as_uint(f);
  return u ^ ((unsigned)((int)u >> 31) | 0x80000000u);
}
static __device__ __forceinline__ float ford_inv(unsigned u) {
  unsigned m = 0x80000000u | ((u >> 31) - 1u);
  return __uint_as_float(u ^ m);
}
static __device__ __forceinline__ unsigned long long shfl_xor_u64(unsigned long long v, int m) {
  unsigned lo = __shfl_xor((unsigned)v, m, 64);
  unsigned hi = __shfl_xor((unsigned)(v >> 32), m, 64);
  return ((unsigned long long)hi << 32) | lo;
}
static __device__ __forceinline__ double shfl_xor_f64(double v, int m) {
  return __longlong_as_double((long long)shfl_xor_u64((unsigned long long)__double_as_longlong(v), m));
}

// ---------------------------------------------------------------------------
// transpose_keys: bf16 + transpose + ksq. Layout: per split (1MB):
// [koct 0..31][key 0..2047][16B] -> knn_main frag loads are linear in step.
// ---------------------------------------------------------------------------
__global__ __launch_bounds__(256) void transpose_keys(const float* __restrict__ keys,
                                                      unsigned char* __restrict__ kbf,
                                                      float* __restrict__ ksq) {
  __shared__ __align__(16) unsigned char T[128 * 512];
  const int t = threadIdx.x;
  const int lane = t & 63;
  const float4* src = (const float4*)(keys + (size_t)blockIdx.x * 128 * DDIM);
#pragma unroll
  for (int j = 0; j < 32; ++j) {
    int g = j * 256 + t;
    float4 v = src[g];
    int key = g >> 6;
    int u = lane >> 1, sub = lane & 1;
    unsigned lo = ((unsigned)f2bf(v.y) << 16) | f2bf(v.x);
    unsigned hi2 = ((unsigned)f2bf(v.w) << 16) | f2bf(v.z);
    unsigned long long p = ((unsigned long long)hi2 << 32) | lo;
    *(unsigned long long*)&T[key * 512 + ((u ^ (key & 7)) << 4) + (sub << 3)] = p;
    float ss = v.x * v.x + v.y * v.y + v.z * v.z + v.w * v.w;
#pragma unroll
    for (int off = 32; off; off >>= 1) ss += __shfl_xor(ss, off, 64);
    if (lane == 0) ksq[blockIdx.x * 128 + key] = ss;
  }
  __syncthreads();
  uint4* dstS = (uint4*)(kbf + (size_t)(blockIdx.x >> 4) * ((size_t)SPLIT_KEYS * 512));
  const int kb0 = (blockIdx.x & 15) * 128;
#pragma unroll
  for (int j = 0; j < 16; ++j) {
    int ou = j * 256 + t;             // 4096 units = 32 koct x 128 keys
    int koct = ou >> 7, keyl = ou & 127;
    dstS[koct * SPLIT_KEYS + kb0 + keyl] =
        *(const uint4*)&T[keyl * 512 + ((koct ^ (keyl & 7)) << 4)];
  }
}

// ---------------------------------------------------------------------------
// xprep: x -> bf16 B-fragments [rowgrp16 0..255][s 0..7][lane 0..63][16B];
// also zero counts[] and init taug[] (runs every launch, before knn_main).
// ---------------------------------------------------------------------------
__global__ __launch_bounds__(256) void xprep(const float* __restrict__ x,
                                             unsigned char* __restrict__ xbf,
                                             unsigned int* __restrict__ counts,
                                             unsigned int* __restrict__ taug) {
  int u = blockIdx.x * 256 + threadIdx.x;      // 131072 units
  int g = u >> 9, s = (u >> 6) & 7, lane = u & 63;
  int row = g * 16 + (lane & 15);
  int d0 = s * 32 + (lane >> 4) * 8;
  const float* p = x + (size_t)row * DDIM + d0;
  float4 a = *(const float4*)p, b = *(const float4*)(p + 4);
  union { unsigned short us[8]; bf16x8 v; } w;
  w.us[0]=f2bf(a.x); w.us[1]=f2bf(a.y); w.us[2]=f2bf(a.z); w.us[3]=f2bf(a.w);
  w.us[4]=f2bf(b.x); w.us[5]=f2bf(b.y); w.us[6]=f2bf(b.z); w.us[7]=f2bf(b.w);
  *(bf16x8*)(xbf + (size_t)u * 16) = w.v;
  if (u < B_ROWS) { counts[u] = 0; taug[u] = 0xFF7FFFFFu; } // ford(FLT_MAX)
}

// ---------------------------------------------------------------------------
// knn_main: NO LDS, NO BARRIERS. 256 thr = 4 independent waves; each wave
// owns 64 rows (4 reg row-sets of 16, feed-4) x one 2048-key split, streaming
// key A-frags straight from L2 into regs, double-buffered 2 steps ahead.
// Grid 512 = 16 row-blocks x 32 splits = 2 blocks/CU (8 free-running waves).
// Selection: tau = min(local bound, global bound).
//  local: 8 streams/(row,split) = (hi x step-parity); tau_l = max of the 8
//  stream minima >= true 8th-best of ANY superset (8 distinct elements).
//  global: taug[row] = atomicMin (ford) of all waves' tau_l -> cross-split
//  tightening. Gate passes => append (score,idx) u64 to per-ROW pool via
//  global atomicAdd. Overflow (cnt>CAP) -> exact rescan in refine:
//  correctness unconditional. Warmup: steps 0..7 build minima (no appends),
//  then steps 0..127 run with tight tau (6% redundant MFMA).
// ---------------------------------------------------------------------------
__global__ __launch_bounds__(256, 2) void knn_main(
    const unsigned char* __restrict__ xbf,
    const unsigned char* __restrict__ kbf,
    const float* __restrict__ ksqg,
    unsigned long long* __restrict__ pool,
    unsigned int* __restrict__ counts,
    unsigned int* __restrict__ taug,
    int CAP) {
  const int t = threadIdx.x;
  const int lane = t & 63;
  const int wv = t >> 6;
  const int lo4 = lane & 15;
  const int hi = lane >> 4;

  const int split = blockIdx.x & (NSPLIT - 1);
  const int rb = (blockIdx.x >> 5) * 256 + wv * 64;  // wave's first row
  const int sb = split * SPLIT_KEYS;

  // ---- x fragments: 4 row-sets x 8 k-slices (128 VGPR), resident
  bf16x8 xb[4][8];
#pragma unroll
  for (int st = 0; st < 4; ++st)
#pragma unroll
    for (int s = 0; s < 8; ++s)
      xb[st][s] = *(const bf16x8*)(xbf +
          (((size_t)(rb / 16 + st) * 8 + s) * 64 + lane) * 16);

  const unsigned char* kb = kbf + (size_t)split * ((size_t)SPLIT_KEYS * 512)
                          + hi * ((size_t)SPLIT_KEYS * 16) + lo4 * 16;

  float m1[4][2];
#pragma unroll
  for (int st = 0; st < 4; ++st) { m1[st][0] = FLT_MAX; m1[st][1] = FLT_MAX; }
  float tg[4] = {FLT_MAX, FLT_MAX, FLT_MAX, FLT_MAX};

  bf16x8 afA[8], afB[8];
  float4 kqA, kqB;
  f32x4 acc[4];

  auto LOADF = [&](bf16x8* af, int kc) {
    const unsigned char* p = kb + (size_t)kc * 256;
#pragma unroll
    for (int s = 0; s < 8; ++s)
      af[s] = *(const bf16x8*)(p + (size_t)s * (SPLIT_KEYS * 64)); // s*4 kocts
  };
  auto LOADQ = [&](int kc) {
    return *(const float4*)(ksqg + sb + kc * 16 + hi * 4);
  };
  auto MM = [&](bf16x8* af) {
#pragma unroll
    for (int st = 0; st < 4; ++st) acc[st] = 0.0f;
#pragma unroll
    for (int s = 0; s < 8; ++s)
#pragma unroll
      for (int st = 0; st < 4; ++st)
        acc[st] = __builtin_amdgcn_mfma_f32_16x16x32_bf16(af[s], xb[st][s], acc[st], 0, 0, 0);
  };
  auto SEL = [&](float4 kq, int kc, int par, bool append) {
#pragma unroll
    for (int st = 0; st < 4; ++st) {
      float sc[4];
#pragma unroll
      for (int i = 0; i < 4; ++i)
        sc[i] = fmaf(-2.0f, acc[st][i], ((const float*)&kq)[i]);
      float mn = fminf(fminf(sc[0], sc[1]), fminf(sc[2], sc[3]));
      m1[st][par] = fminf(m1[st][par], mn);
      if (append) {
        float tl = fmaxf(m1[st][0], m1[st][1]);
        tl = fmaxf(tl, __shfl_xor(tl, 16, 64));
        tl = fmaxf(tl, __shfl_xor(tl, 32, 64));
        float tau = fminf(tl, tg[st]);
        if (mn <= tau) { // rare
          int row = rb + st * 16 + lo4;
#pragma unroll
          for (int i = 0; i < 4; ++i) {
            if (sc[i] <= tau) {
              unsigned slot = atomicAdd(&counts[row], 1u);
              if ((int)slot < CAP)
                pool[(size_t)row * CAP + slot] =
                    ((unsigned long long)ford(sc[i]) << 32)
                  | (unsigned)(sb + kc * 16 + hi * 4 + i);
            }
          }
        }
      }
    }
  };
  auto PUBLISH = [&]() {
#pragma unroll
    for (int st = 0; st < 4; ++st) {
      float tl = fmaxf(m1[st][0], m1[st][1]);
      tl = fmaxf(tl, __shfl_xor(tl, 16, 64));
      tl = fmaxf(tl, __shfl_xor(tl, 32, 64));
      int row = rb + st * 16 + lo4;
      if (hi == 0) atomicMin(&taug[row], ford(tl));
      tg[st] = fminf(tg[st], ford_inv(taug[row]));
    }
  };

  // ---- warmup: steps 0..7, build stream minima, no appends
#pragma unroll 1
  for (int kc = 0; kc < 8; kc += 2) {
    LOADF(afA, kc);     kqA = LOADQ(kc);
    LOADF(afB, kc + 1); kqB = LOADQ(kc + 1);
    MM(afA); SEL(kqA, kc, 0, false);
    MM(afB); SEL(kqB, kc + 1, 1, false);
  }
  PUBLISH();

  // ---- main loop: all 128 steps with tight tau (0..7 redone, now appending)
  LOADF(afA, 0); kqA = LOADQ(0);
  LOADF(afB, 1); kqB = LOADQ(1);
#pragma unroll 1
  for (int kc = 0; kc < NSTEP; kc += 2) {
    const int n0 = (kc + 2 < NSTEP) ? kc + 2 : 0;
    const int n1 = (kc + 3 < NSTEP) ? kc + 3 : 1;
    MM(afA);
    LOADF(afA, n0);                 // prefetch 2 steps ahead (WAR after MFMA)
    SEL(kqA, kc, 0, true);
    kqA = LOADQ(n0);
    MM(afB);
    LOADF(afB, n1);
    SEL(kqB, kc + 1, 1, true);
    kqB = LOADQ(n1);
    if ((kc & 7) == 6) PUBLISH();   // refresh/share tau every 8 steps
  }
}

// ---------------------------------------------------------------------------
// knn_refine: per row (1 wave): scan the row pool (or full exact rescan on
// overflow), tournament top-24 by exact-f32-packed score, fp64 recompute,
// true top-8 (idx tiebreak), average values.
// ---------------------------------------------------------------------------
__global__ __launch_bounds__(64) void knn_refine(
    const float* __restrict__ x,
    const float* __restrict__ keys,
    const float* __restrict__ ksq,
    const float* __restrict__ values,
    const unsigned long long* __restrict__ pool,
    const unsigned int* __restrict__ counts,
    int CAP,
    float* __restrict__ out) {
  __shared__ float4 xl[64];
  const int row = blockIdx.x;
  const int lane = threadIdx.x;

  xl[lane] = ((const float4*)(x + (size_t)row * DDIM))[lane];
  __syncthreads();

  unsigned long long h[8];
#pragma unroll
  for (int i = 0; i < 8; ++i) h[i] = ~0ULL;
  auto insert = [&](unsigned long long v) {
    if (v < h[7]) {
#pragma unroll
      for (int j = 7; j >= 1; --j) {
        unsigned long long a = h[j - 1];
        unsigned long long mx = a > v ? a : v;
        h[j] = (v < h[j]) ? mx : h[j];
      }
      h[0] = h[0] < v ? h[0] : v;
    }
  };

  const unsigned cnt = counts[row];
  if ((int)cnt <= CAP) {
    const unsigned long long* pp = pool + (size_t)row * CAP;
    for (int i = lane; i < (int)cnt; i += 64) insert(pp[i]);
  } else {
    // overflow fallback: exact fp32 full rescan (practically never)
    for (int gk = lane; gk < N_KEYS; gk += 64) {
      const float4* kr = (const float4*)(keys + (size_t)gk * DDIM);
      float acc = 0.f;
#pragma unroll 8
      for (int d = 0; d < 64; ++d) {
        float4 kv = kr[d], xv = xl[d];
        acc = fmaf(kv.x, xv.x, acc); acc = fmaf(kv.y, xv.y, acc);
        acc = fmaf(kv.z, xv.z, acc); acc = fmaf(kv.w, xv.w, acc);
      }
      float sc = fmaf(-2.0f, acc, ksq[gk]);
      insert(((unsigned long long)ford(sc) << 32) | (unsigned)gk);
    }
  }

  // ---- tournament: top-24 (u64 entries unique: idx in low bits)
  int myidx = 0;
#pragma unroll 1
  for (int r = 0; r < 24; ++r) {
    unsigned long long m = h[0];
#pragma unroll
    for (int off = 32; off; off >>= 1) {
      unsigned long long o = shfl_xor_u64(m, off);
      m = o < m ? o : m;
    }
    if (lane == r) myidx = (int)(m & 0xFFFFu);
    if (h[0] == m) {
#pragma unroll
      for (int i = 0; i < 7; ++i) h[i] = h[i + 1];
      h[7] = ~0ULL;
    }
  }

  // ---- exact fp64 distance for my candidate
  double dv = 1e300;
  if (lane < 24) {
    const float4* kr = (const float4*)(keys + (size_t)myidx * DDIM);
    double s = 0.0;
#pragma unroll 8
    for (int d = 0; d < 64; ++d) {
      float4 kv = kr[d], xv = xl[d];
      double d0 = (double)xv.x - (double)kv.x;
      double d1 = (double)xv.y - (double)kv.y;
      double d2 = (double)xv.z - (double)kv.z;
      double d3 = (double)xv.w - (double)kv.w;
      s += d0 * d0 + d1 * d1 + d2 * d2 + d3 * d3;
    }
    dv = s;
  }

  int di = myidx;
  int chosen[8];
#pragma unroll
  for (int r = 0; r < 8; ++r) {
    double m = dv; int mi = di;
#pragma unroll
    for (int off = 32; off; off >>= 1) {
      double om = shfl_xor_f64(m, off);
      int omi = __shfl_xor(mi, off, 64);
      if (om < m || (om == m && omi < mi)) { m = om; mi = omi; }
    }
    chosen[r] = mi;
    if (di == mi && dv < 1e300) dv = 1e300;
  }

  if (lane < NCH) {
    double a = 0.0;
#pragma unroll
    for (int r = 0; r < 8; ++r) a += (double)values[(size_t)chosen[r] * NCH + lane];
    out[row * NCH + lane] = (float)(a * 0.125);
  }
}

// ---------------------------------------------------------------------------
extern "C" void kernel_launch(void* const* d_in, const int* in_sizes, int n_in,
                              void* d_out, int out_size, void* d_ws, size_t ws_size,
                              hipStream_t stream) {
  (void)in_sizes; (void)n_in; (void)out_size;
  const float* x      = (const float*)d_in[0];
  const float* keys   = (const float*)d_in[1];
  const float* values = (const float*)d_in[2];
  float* out = (float*)d_out;

  char* ws = (char*)d_ws;
  unsigned char* kbf   = (unsigned char*)ws;                      // 32 MB keys (frag layout)
  unsigned char* xbf   = (unsigned char*)(ws + 33554432);         // 2 MB x frags
  float*         ksq   = (float*)(ws + 33554432 + 2097152);       // 256 KB
  unsigned int*  counts= (unsigned int*)(ws + 33554432 + 2097152 + 262144); // 16 KB
  unsigned int*  taug  = (unsigned int*)(ws + 33554432 + 2097152 + 262144 + 16384); // 16 KB
  unsigned long long* pool =
      (unsigned long long*)(ws + 33554432 + 2097152 + 262144 + 32768);

  size_t base = 33554432 + 2097152 + 262144 + 32768;
  size_t cap = (ws_size > base) ? (ws_size - base) / ((size_t)B_ROWS * 8) : 256;
  if (cap < 256) cap = 256;
  if (cap > 2048) cap = 2048;
  int CAP = (int)cap;

  transpose_keys<<<N_KEYS / 128, 256, 0, stream>>>(keys, kbf, ksq);
  xprep<<<512, 256, 0, stream>>>(x, xbf, counts, taug);
  knn_main<<<(B_ROWS / 256) * NSPLIT, 256, 0, stream>>>(
      xbf, kbf, ksq, pool, counts, taug, CAP);
  knn_refine<<<B_ROWS, 64, 0, stream>>>(x, keys, ksq, values, pool, counts, CAP, out);
}

// Round 9
// 301.264 us; speedup vs baseline: 3.3440x; 3.0508x over previous
//
#include <hip/hip_runtime.h>
#include <stdint.h>
#include <float.h>

// x[4096,256] f32, keys[65536,256] f32, values[65536,10] f32, k=8 (hardcoded).
#define B_ROWS 4096
#define N_KEYS 65536
#define DDIM 256
#define NCH 10

#define NSPLIT 8
#define SPLIT_KEYS (N_KEYS / NSPLIT)       // 8192
#define ROWS_PER_BLK 64
#define CHUNK_KEYS 64
#define NCHUNK (SPLIT_KEYS / CHUNK_KEYS)   // 128

typedef float f32x4 __attribute__((ext_vector_type(4)));
typedef short bf16x8 __attribute__((ext_vector_type(8)));

static __device__ __forceinline__ unsigned short f2bf(float f) {
  unsigned u = __float_as_uint(f);
  return (unsigned short)((u + 0x7FFFu + ((u >> 16) & 1u)) >> 16);
}
static __device__ __forceinline__ unsigned ford(float f) {
  unsigned u = __float_as_uint(f);
  return u ^ ((unsigned)((int)u >> 31) | 0x80000000u);
}
static __device__ __forceinline__ unsigned long long shfl_xor_u64(unsigned long long v, int m) {
  unsigned lo = __shfl_xor((unsigned)v, m, 64);
  unsigned hi = __shfl_xor((unsigned)(v >> 32), m, 64);
  return ((unsigned long long)hi << 32) | lo;
}
static __device__ __forceinline__ double shfl_xor_f64(double v, int m) {
  return __longlong_as_double((long long)shfl_xor_u64((unsigned long long)__double_as_longlong(v), m));
}
static __device__ __forceinline__ void gl_lds16(const void* g, void* l) {
  __builtin_amdgcn_global_load_lds(
      (const __attribute__((address_space(1))) unsigned int*)g,
      (__attribute__((address_space(3))) unsigned int*)l, 16, 0, 0);
}

// ---------------------------------------------------------------------------
// transpose_keys: bf16-convert + transpose + fused ksq. Output: per 64-key
// record [doct 0..31][key 0..63][16B] (32KB): knn_main staging is a LINEAR
// copy; A-frag ds_read_b128s are 256B-contiguous per 16-lane phase.
// ---------------------------------------------------------------------------
__global__ __launch_bounds__(256) void transpose_keys(const float* __restrict__ keys,
                                                      unsigned char* __restrict__ kbf,
                                                      float* __restrict__ ksq) {
  __shared__ __align__(16) unsigned char T[128 * 512];
  const int t = threadIdx.x;
  const int lane = t & 63;
  const float4* src = (const float4*)(keys + (size_t)blockIdx.x * 128 * DDIM);
#pragma unroll
  for (int j = 0; j < 32; ++j) {
    int g = j * 256 + t;
    float4 v = src[g];
    int key = g >> 6;
    int u = lane >> 1, sub = lane & 1;
    unsigned lo = ((unsigned)f2bf(v.y) << 16) | f2bf(v.x);
    unsigned hi2 = ((unsigned)f2bf(v.w) << 16) | f2bf(v.z);
    unsigned long long p = ((unsigned long long)hi2 << 32) | lo;
    *(unsigned long long*)&T[key * 512 + ((u ^ (key & 7)) << 4) + (sub << 3)] = p;
    float ss = v.x * v.x + v.y * v.y + v.z * v.z + v.w * v.w;
#pragma unroll
    for (int off = 32; off; off >>= 1) ss += __shfl_xor(ss, off, 64);
    if (lane == 0) ksq[blockIdx.x * 128 + key] = ss;
  }
  __syncthreads();
  uint4* dst = (uint4*)(kbf + (size_t)blockIdx.x * 65536);
#pragma unroll
  for (int j = 0; j < 16; ++j) {
    int ou = j * 256 + t;
    int c64 = ou >> 11, rem = ou & 2047;
    int koct = rem >> 6, key64 = rem & 63;
    int keyl = c64 * 64 + key64;
    dst[ou] = *(const uint4*)&T[keyl * 512 + ((koct ^ (keyl & 7)) << 4)];
  }
}

// ---------------------------------------------------------------------------
// knn_main (r5 champion + dephasing + ksq-fold + setprio):
// 512 thr = 8 waves = 4 key-quarters (mw, 16 keys) x 2 row-halves (ws, 32
// rows = 2 reg sets). 64 rows x one 8192-key split in 128 chunks of 64 keys.
// 2 blocks/CU; co-resident blocks process chunks ROTATED by 64 so their
// LDS/MFMA/VALU bursts interleave instead of convoying.
// ksq is folded into the MFMA C-init (x pre-scaled by -2), so scores come
// straight out of the accumulator. Selection: tau filter + append (8 paired
// streams/row; tau_row = max of 8 stream minima >= true 8th-best; overflow
// -> exact rescan in refine, correctness unconditional).
// ---------------------------------------------------------------------------
__global__ __launch_bounds__(512, 4) void knn_main(
    const float* __restrict__ x,
    const unsigned char* __restrict__ kbf,
    const float* __restrict__ ksqg,
    unsigned int* __restrict__ pools,
    unsigned int* __restrict__ counts,
    int CAP) {
  __shared__ __align__(16) unsigned char tiles[2][32768]; // 64KB double buffer
  __shared__ float tauh[2][2][16][4]; // [set][ws][lo4][mw]; monotone, race-benign
  __shared__ unsigned int rowcnt[64];

  const int t = threadIdx.x;
  const int lane = t & 63;
  const int wv = t >> 6;          // 0..7
  const int mw = wv & 3;          // key quarter (16 keys)
  const int ws = wv >> 2;         // row half (32 rows)
  const int lo4 = lane & 15;
  const int hi = lane >> 4;

  const int split = blockIdx.x & (NSPLIT - 1);
  const int rb = (blockIdx.x >> 3) * ROWS_PER_BLK;
  const int sb = split * SPLIT_KEYS;
  const int rot = ((blockIdx.x >> 8) & 1) * (NCHUNK / 2); // de-phase twin block

  const int xrow0 = rb + ws * 32 + lo4;
  const int xrow1 = xrow0 + 16;
  const int rl0 = ws * 32 + lo4, rl1 = rl0 + 16;

  // ---- x fragments PRE-SCALED by -2 (folds the -2 into the MFMA)
  bf16x8 xb0[8], xb1[8];
#pragma unroll
  for (int s = 0; s < 8; ++s) {
    const float* p0 = x + (size_t)xrow0 * DDIM + s * 32 + hi * 8;
    const float* p1 = x + (size_t)xrow1 * DDIM + s * 32 + hi * 8;
    float4 a = *(const float4*)p0, b = *(const float4*)(p0 + 4);
    float4 c = *(const float4*)p1, d = *(const float4*)(p1 + 4);
    union { unsigned short us[8]; bf16x8 v; } u0, u1;
    u0.us[0]=f2bf(-2.f*a.x); u0.us[1]=f2bf(-2.f*a.y); u0.us[2]=f2bf(-2.f*a.z); u0.us[3]=f2bf(-2.f*a.w);
    u0.us[4]=f2bf(-2.f*b.x); u0.us[5]=f2bf(-2.f*b.y); u0.us[6]=f2bf(-2.f*b.z); u0.us[7]=f2bf(-2.f*b.w);
    u1.us[0]=f2bf(-2.f*c.x); u1.us[1]=f2bf(-2.f*c.y); u1.us[2]=f2bf(-2.f*c.z); u1.us[3]=f2bf(-2.f*c.w);
    u1.us[4]=f2bf(-2.f*d.x); u1.us[5]=f2bf(-2.f*d.y); u1.us[6]=f2bf(-2.f*d.z); u1.us[7]=f2bf(-2.f*d.w);
    xb0[s] = u0.v; xb1[s] = u1.v;
  }

  if (t < 64) rowcnt[t] = 0;

  float smin0 = FLT_MAX, smin1 = FLT_MAX;
  const unsigned char* srcbase = kbf + ((size_t)(split * NCHUNK) << 15);
  const size_t pb0 = ((size_t)xrow0 * NSPLIT + split) * (size_t)CAP;
  const size_t pb1 = ((size_t)xrow1 * NSPLIT + split) * (size_t)CAP;

  auto CIDX = [&](int c) { return (c + rot) & (NCHUNK - 1); };

  auto STAGE = [&](int c, int buf) { // linear 32KB, 4 x 16B per thread
    const unsigned char* src = srcbase + ((size_t)CIDX(c) << 15);
    unsigned char* wb = (unsigned char*)tiles[buf] + ((wv * 64) << 4);
#pragma unroll
    for (int i = 0; i < 4; ++i)
      gl_lds16(src + (((i * 512) + t) << 4), wb + ((i * 512) << 4));
  };
  auto LOADQ = [&](int c) {
    return *(const float4*)(ksqg + sb + CIDX(c) * CHUNK_KEYS + mw * 16 + hi * 4);
  };

  f32x4 a0, a1;
  float4 kqc, kqn;

  auto COMPUTE = [&](int c) { // acc init = ksq (fold), then MFMA
    const unsigned char* tile = tiles[c & 1];
    f32x4 ini;
    ini[0] = kqc.x; ini[1] = kqc.y; ini[2] = kqc.z; ini[3] = kqc.w;
    a0 = ini; a1 = ini;
    __builtin_amdgcn_s_setprio(1);
#pragma unroll
    for (int s = 0; s < 8; ++s) {
      const unsigned char* rp = tile + (s * 4 + hi) * 1024 + (mw * 16 + lo4) * 16;
      bf16x8 af = *(const bf16x8*)rp;
      a0 = __builtin_amdgcn_mfma_f32_16x16x32_bf16(af, xb0[s], a0, 0, 0, 0);
      a1 = __builtin_amdgcn_mfma_f32_16x16x32_bf16(af, xb1[s], a1, 0, 0, 0);
    }
    __builtin_amdgcn_s_setprio(0);
  };

  auto SEL = [&](int c, bool append, float tau0, float tau1) {
    // scores are the accumulators directly (ksq - 2*x.k)
    float mb0 = fminf(fminf(a0[0], a0[1]), fminf(a0[2], a0[3]));
    float mb1 = fminf(fminf(a1[0], a1[1]), fminf(a1[2], a1[3]));
    smin0 = fminf(smin0, mb0);
    smin1 = fminf(smin1, mb1);
    if (append) {
      const int kloc = CIDX(c) * CHUNK_KEYS + mw * 16 + hi * 4;
      if (mb0 <= tau0) { // rare
#pragma unroll
        for (int i = 0; i < 4; ++i) {
          if (a0[i] <= tau0) {
            unsigned slot = atomicAdd(&rowcnt[rl0], 1u);
            if ((int)slot < CAP)
              pools[pb0 + slot] = (ford(a0[i]) & 0xFFFFE000u) | (unsigned)(kloc + i);
          }
        }
      }
      if (mb1 <= tau1) {
#pragma unroll
        for (int i = 0; i < 4; ++i) {
          if (a1[i] <= tau1) {
            unsigned slot = atomicAdd(&rowcnt[rl1], 1u);
            if ((int)slot < CAP)
              pools[pb1 + slot] = (ford(a1[i]) & 0xFFFFE000u) | (unsigned)(kloc + i);
          }
        }
      }
    }
  };

  auto RDTAU = [&](float& tau0, float& tau1) {
    float4 t0 = *(const float4*)&tauh[0][ws][lo4][0];
    float4 t1 = *(const float4*)&tauh[1][ws][lo4][0];
    tau0 = fmaxf(fmaxf(t0.x, t0.y), fmaxf(t0.z, t0.w));
    tau1 = fmaxf(fmaxf(t1.x, t1.y), fmaxf(t1.z, t1.w));
  };

  auto PUBLISH = [&]() {
    // pair streams across hi (xor16 -> min), then max over the 2 pairs (xor32)
    float p0 = fminf(smin0, __shfl_xor(smin0, 16, 64));
    p0 = fmaxf(p0, __shfl_xor(p0, 32, 64));
    float p1 = fminf(smin1, __shfl_xor(smin1, 16, 64));
    p1 = fmaxf(p1, __shfl_xor(p1, 32, 64));
    if (hi == 0) {
      tauh[0][ws][lo4][mw] = p0;
      tauh[1][ws][lo4][mw] = p1;
    }
  };

  // ---- prologue + peeled chunk 0 (build tau before any appends)
  STAGE(0, 0);
  kqc = LOADQ(0);
  __syncthreads();
  STAGE(1, 1);
  kqn = LOADQ(1);
  COMPUTE(0);
  SEL(0, false, 0.f, 0.f);   // smin only
  PUBLISH();
  __syncthreads();           // tau visible (drains stage(1) too — prologue only)
  {
    float tau0, tau1;
    RDTAU(tau0, tau1);
    SEL(0, true, tau0, tau1); // append chunk 0 with fresh tau
  }
  kqc = kqn;

#pragma unroll 1
  for (int c = 1; c < NCHUNK; ++c) {
    const int cn = (c + 1 < NCHUNK) ? c + 1 : c; // uniform tail (re-stage ok)
    STAGE(cn, (c + 1) & 1);
    kqn = LOADQ(cn);
    float tau0, tau1;
    RDTAU(tau0, tau1);       // lagged/racy tau: always a valid upper bound
    COMPUTE(c);
    SEL(c, true, tau0, tau1);
    if (c & 1) PUBLISH();
    kqc = kqn;
    __syncthreads();         // tile consumed; next stage drained
  }

  __syncthreads();
  if (t < 64) counts[(size_t)(rb + t) * NSPLIT + split] = rowcnt[t];
}

// ---------------------------------------------------------------------------
// knn_refine: per row (1 wave): scan the row's 8 pools (or exact-rescan any
// overflowed split) into per-lane top-8, tournament top-24 by quantized
// score, fp64-exact recompute, true top-8 (idx tiebreak), average values.
// ---------------------------------------------------------------------------
__global__ __launch_bounds__(64) void knn_refine(
    const float* __restrict__ x,
    const float* __restrict__ keys,
    const float* __restrict__ ksq,
    const float* __restrict__ values,
    const unsigned int* __restrict__ pools,
    const unsigned int* __restrict__ counts,
    int CAP,
    float* __restrict__ out) {
  __shared__ float4 xl[64];
  const int row = blockIdx.x;
  const int lane = threadIdx.x;

  xl[lane] = ((const float4*)(x + (size_t)row * DDIM))[lane];
  __syncthreads();

  unsigned long long h[8];
#pragma unroll
  for (int i = 0; i < 8; ++i) h[i] = ~0ULL;

  auto insert = [&](unsigned long long v) {
    if (v < h[7]) {
#pragma unroll
      for (int j = 7; j >= 1; --j) {
        unsigned long long a = h[j - 1];
        unsigned long long mx = a > v ? a : v;
        h[j] = (v < h[j]) ? mx : h[j];
      }
      h[0] = h[0] < v ? h[0] : v;
    }
  };

  for (int s = 0; s < NSPLIT; ++s) {
    unsigned cnt = counts[(size_t)row * NSPLIT + s];
    if ((int)cnt <= CAP) {
      const unsigned int* pp = pools + ((size_t)row * NSPLIT + s) * (size_t)CAP;
      for (int i = lane; i < (int)cnt; i += 64) {
        unsigned p = pp[i];
        unsigned long long v = ((unsigned long long)p << 17)
                             | (unsigned)(s * SPLIT_KEYS + (p & 0x1FFFu));
        insert(v);
      }
    } else {
      // overflow fallback: exact fp32 rescan of this split
      for (int kk = lane; kk < SPLIT_KEYS; kk += 64) {
        int gk = s * SPLIT_KEYS + kk;
        const float4* kr = (const float4*)(keys + (size_t)gk * DDIM);
        float acc = 0.f;
#pragma unroll 8
        for (int d = 0; d < 64; ++d) {
          float4 kv = kr[d], xv = xl[d];
          acc = fmaf(kv.x, xv.x, acc); acc = fmaf(kv.y, xv.y, acc);
          acc = fmaf(kv.z, xv.z, acc); acc = fmaf(kv.w, xv.w, acc);
        }
        float sc = fmaf(-2.0f, acc, ksq[gk]);
        unsigned p = (ford(sc) & 0xFFFFE000u) | (unsigned)kk;
        insert(((unsigned long long)p << 17) | (unsigned)gk);
      }
    }
  }

  // ---- tournament: top-24 by quantized score (u64 unique: gk in low bits)
  int myidx = 0;
#pragma unroll 1
  for (int r = 0; r < 24; ++r) {
    unsigned long long m = h[0];
#pragma unroll
    for (int off = 32; off; off >>= 1) {
      unsigned long long o = shfl_xor_u64(m, off);
      m = o < m ? o : m;
    }
    if (lane == r) myidx = (int)(m & 0x1FFFFu);
    if (h[0] == m) {
#pragma unroll
      for (int i = 0; i < 7; ++i) h[i] = h[i + 1];
      h[7] = ~0ULL;
    }
  }

  // ---- exact fp64 distance for my candidate
  double dv = 1e300;
  if (lane < 24) {
    const float4* kr = (const float4*)(keys + (size_t)myidx * DDIM);
    double s = 0.0;
#pragma unroll 8
    for (int d = 0; d < 64; ++d) {
      float4 kv = kr[d], xv = xl[d];
      double d0 = (double)xv.x - (double)kv.x;
      double d1 = (double)xv.y - (double)kv.y;
      double d2 = (double)xv.z - (double)kv.z;
      double d3 = (double)xv.w - (double)kv.w;
      s += d0 * d0 + d1 * d1 + d2 * d2 + d3 * d3;
    }
    dv = s;
  }

  int di = myidx;
  int chosen[8];
#pragma unroll
  for (int r = 0; r < 8; ++r) {
    double m = dv; int mi = di;
#pragma unroll
    for (int off = 32; off; off >>= 1) {
      double om = shfl_xor_f64(m, off);
      int omi = __shfl_xor(mi, off, 64);
      if (om < m || (om == m && omi < mi)) { m = om; mi = omi; }
    }
    chosen[r] = mi;
    if (di == mi && dv < 1e300) dv = 1e300;
  }

  if (lane < NCH) {
    double a = 0.0;
#pragma unroll
    for (int r = 0; r < 8; ++r) a += (double)values[(size_t)chosen[r] * NCH + lane];
    out[row * NCH + lane] = (float)(a * 0.125);
  }
}

// ---------------------------------------------------------------------------
extern "C" void kernel_launch(void* const* d_in, const int* in_sizes, int n_in,
                              void* d_out, int out_size, void* d_ws, size_t ws_size,
                              hipStream_t stream) {
  (void)in_sizes; (void)n_in; (void)out_size;
  const float* x      = (const float*)d_in[0];
  const float* keys   = (const float*)d_in[1];
  const float* values = (const float*)d_in[2];
  float* out = (float*)d_out;

  char* ws = (char*)d_ws;
  unsigned char* kbf = (unsigned char*)ws;                            // 32 MB transposed bf16 keys
  float* ksq   = (float*)(ws + 33554432);                             // 256 KB
  unsigned int* counts = (unsigned int*)(ws + 33554432 + 262144);     // 128 KB
  unsigned int* pools  = (unsigned int*)(ws + 33554432 + 262144 + 131072);

  size_t base = 33554432 + 262144 + 131072;
  size_t cap = (ws_size > base) ? (ws_size - base) / ((size_t)B_ROWS * NSPLIT * 4) : 32;
  if (cap < 32) cap = 32;
  if (cap > 2048) cap = 2048;
  int CAP = (int)cap;

  transpose_keys<<<N_KEYS / 128, 256, 0, stream>>>(keys, kbf, ksq);
  knn_main<<<(B_ROWS / ROWS_PER_BLK) * NSPLIT, 512, 0, stream>>>(
      x, kbf, ksq, pools, counts, CAP);
  knn_refine<<<B_ROWS, 64, 0, stream>>>(x, keys, ksq, values, pools, counts, CAP, out);
}